// Round 5
// baseline (41.617 us; speedup 1.0000x reference)
//
#include <hip/hip_runtime.h>

// UnitaryQuantizer: masked elementwise phase quantization.
// out[b][r][c] = (r + c <= N-2) ? quant(x[b][r][c]) : 0
// N = 512, B = 128, f32 in/out. Memory-bound.
//
// Predicated loads: masked positions (r+c > 510, ~half) never read input.
// NT *loads* (evict-first) + cached stores: give the 134 MB output, which is
// rewritten every graph replay, priority to stay Infinity-Cache-resident;
// the streaming 67 MB input gets no retention (it has zero reuse anyway).
// (R3 showed nt on the STORE side is wrong: 38.1 vs 36.2 us.)

#define N_DIM 512

typedef float floatx4 __attribute__((ext_vector_type(4)));

__global__ __launch_bounds__(256) void UnitaryQuantizer_kernel(
    const float* __restrict__ x, float* __restrict__ out, int n4)
{
    constexpr double PI_D   = 3.14159265358979323846;
    constexpr float TWO_PI  = (float)(2.0 * PI_D);
    constexpr float INV_2PI = (float)(1.0 / (2.0 * PI_D));
    constexpr float THR     = (float)(1.5 * PI_D);                 // wrap threshold
    constexpr float PMIN    = (float)((0.015625 - 0.5) * PI_D);    // (0.5^6 - 0.5)*pi
    constexpr float PMAX    = (float)((1.5 - 0.0078125) * PI_D);   // (1.5 - 0.5^7)*pi
    constexpr float RATIO   = (float)((((1.5 - 0.0078125) * PI_D) -
                                       ((0.015625 - 0.5) * PI_D)) / 255.0);

    const floatx4* __restrict__ x4 = reinterpret_cast<const floatx4*>(x);
    floatx4* __restrict__ o4 = reinterpret_cast<floatx4*>(out);

    const int stride = gridDim.x * blockDim.x;
    for (int t = blockIdx.x * blockDim.x + threadIdx.x; t < n4; t += stride) {
        const int e = t << 2;              // linear element index of lane's float4
        const int r = (e >> 9) & (N_DIM - 1);
        const int c = e & (N_DIM - 1);     // cols c..c+3, same row (512 % 4 == 0)

        floatx4 o = {0.0f, 0.0f, 0.0f, 0.0f};

        if (r + c <= N_DIM - 2) {          // at least one live element -> load
            const floatx4 v = __builtin_nontemporal_load(&x4[t]);  // evict-first
            #pragma unroll
            for (int j = 0; j < 4; ++j) {
                float m = v[j];
                // mod 2pi (floor-based; exact identity for m in [0, 2pi))
                m = m - TWO_PI * floorf(m * INV_2PI);
                // wrap (1.5pi, 2pi) -> negative
                if (m > THR) m -= TWO_PI;
                // clip
                m = fminf(fmaxf(m, PMIN), PMAX);
                // quantize to 255 steps, round-half-even like jnp.round
                float q = rintf((m - PMIN) / RATIO) * RATIO + PMIN;
                // per-element mask at the diagonal boundary
                o[j] = ((r + c + j) <= (N_DIM - 2)) ? q : 0.0f;
            }
        }

        o4[t] = o;                         // plain cached dwordx4 store
    }
}

extern "C" void kernel_launch(void* const* d_in, const int* in_sizes, int n_in,
                              void* d_out, int out_size, void* d_ws, size_t ws_size,
                              hipStream_t stream) {
    const float* x = (const float*)d_in[0];
    float* out = (float*)d_out;
    const int n  = in_sizes[0];     // 128*512*512 = 33,554,432
    const int n4 = n >> 2;          // float4 count

    const int block = 256;
    const int grid  = 2048;         // ~8 blocks/CU, grid-stride the rest
    UnitaryQuantizer_kernel<<<grid, block, 0, stream>>>(x, out, n4);
}

// Round 6
// 34.752 us; speedup vs baseline: 1.1975x; 1.1975x over previous
//
#include <hip/hip_runtime.h>

// UnitaryQuantizer: masked elementwise phase quantization.
// out[b][r][c] = (r + c <= N-2) ? quant(x[b][r][c]) : 0
// N = 512, B = 128, f32 in/out. Memory-bound.
//
// R4 base (36.15 us, plain cached loads+stores, predicated on the mask) +
// 2x float4 per thread per sweep: two independent loads issued back-to-back
// for MLP before either compute chain. No cache hints: R3 showed nt-store
// costs ~2 us, R5 showed nt-load costs ~5.5 us (input L3 retention is real).

#define N_DIM 512

typedef float floatx4 __attribute__((ext_vector_type(4)));

__device__ __forceinline__ floatx4 quant4(floatx4 v, int r, int c) {
    constexpr double PI_D   = 3.14159265358979323846;
    constexpr float TWO_PI  = (float)(2.0 * PI_D);
    constexpr float INV_2PI = (float)(1.0 / (2.0 * PI_D));
    constexpr float THR     = (float)(1.5 * PI_D);
    constexpr float PMIN    = (float)((0.015625 - 0.5) * PI_D);
    constexpr float PMAX    = (float)((1.5 - 0.0078125) * PI_D);
    constexpr float RATIO   = (float)((((1.5 - 0.0078125) * PI_D) -
                                       ((0.015625 - 0.5) * PI_D)) / 255.0);
    floatx4 o;
    #pragma unroll
    for (int j = 0; j < 4; ++j) {
        float m = v[j];
        m = m - TWO_PI * floorf(m * INV_2PI);   // mod 2pi (exact for [0,2pi))
        if (m > THR) m -= TWO_PI;               // wrap (1.5pi,2pi) -> negative
        m = fminf(fmaxf(m, PMIN), PMAX);        // clip
        float q = rintf((m - PMIN) / RATIO) * RATIO + PMIN;
        o[j] = ((r + c + j) <= (N_DIM - 2)) ? q : 0.0f;
    }
    return o;
}

__global__ __launch_bounds__(256) void UnitaryQuantizer_kernel(
    const float* __restrict__ x, float* __restrict__ out, int n4)
{
    const floatx4* __restrict__ x4 = reinterpret_cast<const floatx4*>(x);
    floatx4* __restrict__ o4 = reinterpret_cast<floatx4*>(out);

    const int span   = gridDim.x * blockDim.x;   // threads in grid
    const int stride = span * 2;                 // 2 float4 per thread per sweep

    for (int t0 = blockIdx.x * blockDim.x + threadIdx.x; t0 < n4; t0 += stride) {
        const int t1 = t0 + span;
        const bool has1 = (t1 < n4);

        const int e0 = t0 << 2, e1 = t1 << 2;
        const int r0 = (e0 >> 9) & (N_DIM - 1), c0 = e0 & (N_DIM - 1);
        const int r1 = (e1 >> 9) & (N_DIM - 1), c1 = e1 & (N_DIM - 1);
        const bool live0 = (r0 + c0 <= N_DIM - 2);
        const bool live1 = has1 && (r1 + c1 <= N_DIM - 2);

        // Issue both loads before any compute (MLP).
        floatx4 v0 = {0.f, 0.f, 0.f, 0.f};
        floatx4 v1 = {0.f, 0.f, 0.f, 0.f};
        if (live0) v0 = x4[t0];
        if (live1) v1 = x4[t1];

        floatx4 o0 = {0.f, 0.f, 0.f, 0.f};
        floatx4 o1 = {0.f, 0.f, 0.f, 0.f};
        if (live0) o0 = quant4(v0, r0, c0);
        if (live1) o1 = quant4(v1, r1, c1);

        o4[t0] = o0;
        if (has1) o4[t1] = o1;
    }
}

extern "C" void kernel_launch(void* const* d_in, const int* in_sizes, int n_in,
                              void* d_out, int out_size, void* d_ws, size_t ws_size,
                              hipStream_t stream) {
    const float* x = (const float*)d_in[0];
    float* out = (float*)d_out;
    const int n  = in_sizes[0];     // 128*512*512 = 33,554,432
    const int n4 = n >> 2;          // 8,388,608 float4

    const int block = 256;
    const int grid  = 4096;         // 4096*256*2 = 2,097,152 float4/sweep -> exactly 4 sweeps
    UnitaryQuantizer_kernel<<<grid, block, 0, stream>>>(x, out, n4);
}

// Round 7
// 33.639 us; speedup vs baseline: 1.2372x; 1.0331x over previous
//
#include <hip/hip_runtime.h>

// UnitaryQuantizer: masked elementwise phase quantization.
// out[b][r][c] = (r + c <= N-2) ? quant(x[b][r][c]) : 0
// N = 512, B = 128, f32 in/out. Memory-bound (201 MB compulsory traffic:
// 67 MB live input read + 134 MB output write).
//
// R6 base (34.75 us) -> loop-free: 8192 blocks x 256 thr x 4 float4 = n4
// exactly. 4 independent predicated loads issued before any compute (4-deep
// MLP), no trip-count branches. No cache hints (R3: nt-store -2us worse,
// R5: nt-load -5.5us worse; L3 retention of the live input is real).

#define N_DIM 512

typedef float floatx4 __attribute__((ext_vector_type(4)));

__device__ __forceinline__ floatx4 quant4(floatx4 v, int rc) {
    constexpr double PI_D   = 3.14159265358979323846;
    constexpr float TWO_PI  = (float)(2.0 * PI_D);
    constexpr float INV_2PI = (float)(1.0 / (2.0 * PI_D));
    constexpr float THR     = (float)(1.5 * PI_D);
    constexpr float PMIN    = (float)((0.015625 - 0.5) * PI_D);
    constexpr float PMAX    = (float)((1.5 - 0.0078125) * PI_D);
    constexpr float RATIO   = (float)((((1.5 - 0.0078125) * PI_D) -
                                       ((0.015625 - 0.5) * PI_D)) / 255.0);
    floatx4 o;
    #pragma unroll
    for (int j = 0; j < 4; ++j) {
        float m = v[j];
        m = m - TWO_PI * floorf(m * INV_2PI);   // mod 2pi (exact for [0,2pi))
        if (m > THR) m -= TWO_PI;               // wrap (1.5pi,2pi) -> negative
        m = fminf(fmaxf(m, PMIN), PMAX);        // clip
        float q = rintf((m - PMIN) / RATIO) * RATIO + PMIN;
        o[j] = ((rc + j) <= (N_DIM - 2)) ? q : 0.0f;
    }
    return o;
}

// Exact-shape kernel: gridDim.x*blockDim.x*4 == n4, no bounds checks.
__global__ __launch_bounds__(256) void UnitaryQuantizer_kernel(
    const float* __restrict__ x, float* __restrict__ out)
{
    const floatx4* __restrict__ x4 = reinterpret_cast<const floatx4*>(x);
    floatx4* __restrict__ o4 = reinterpret_cast<floatx4*>(out);

    const int span = gridDim.x * blockDim.x;          // 2,097,152
    const int t    = blockIdx.x * blockDim.x + threadIdx.x;

    int   idx[4];
    int   rc[4];
    bool  live[4];
    #pragma unroll
    for (int k = 0; k < 4; ++k) {
        idx[k] = t + k * span;
        const int e = idx[k] << 2;
        const int r = (e >> 9) & (N_DIM - 1);
        const int c = e & (N_DIM - 1);
        rc[k]   = r + c;
        live[k] = (rc[k] <= N_DIM - 2);
    }

    // Issue all 4 (predicated) loads before any compute: 4-deep MLP.
    floatx4 v[4];
    #pragma unroll
    for (int k = 0; k < 4; ++k) {
        v[k] = floatx4{0.f, 0.f, 0.f, 0.f};
        if (live[k]) v[k] = x4[idx[k]];
    }

    #pragma unroll
    for (int k = 0; k < 4; ++k) {
        floatx4 o = {0.f, 0.f, 0.f, 0.f};
        if (live[k]) o = quant4(v[k], rc[k]);
        o4[idx[k]] = o;
    }
}

// Generic fallback (never taken for the 128x512x512 shape).
__global__ __launch_bounds__(256) void UnitaryQuantizer_generic(
    const float* __restrict__ x, float* __restrict__ out, int n4)
{
    const floatx4* __restrict__ x4 = reinterpret_cast<const floatx4*>(x);
    floatx4* __restrict__ o4 = reinterpret_cast<floatx4*>(out);
    const int stride = gridDim.x * blockDim.x;
    for (int t = blockIdx.x * blockDim.x + threadIdx.x; t < n4; t += stride) {
        const int e = t << 2;
        const int r = (e >> 9) & (N_DIM - 1);
        const int c = e & (N_DIM - 1);
        floatx4 o = {0.f, 0.f, 0.f, 0.f};
        if (r + c <= N_DIM - 2) o = quant4(x4[t], r + c);
        o4[t] = o;
    }
}

extern "C" void kernel_launch(void* const* d_in, const int* in_sizes, int n_in,
                              void* d_out, int out_size, void* d_ws, size_t ws_size,
                              hipStream_t stream) {
    const float* x = (const float*)d_in[0];
    float* out = (float*)d_out;
    const int n  = in_sizes[0];     // 128*512*512 = 33,554,432
    const int n4 = n >> 2;          // 8,388,608 float4

    const int block = 256;
    const int grid  = 8192;         // 8192*256*4 = 8,388,608 = n4 exactly

    if (n4 == grid * block * 4) {
        UnitaryQuantizer_kernel<<<grid, block, 0, stream>>>(x, out);
    } else {
        UnitaryQuantizer_generic<<<2048, block, 0, stream>>>(x, out, n4);
    }
}